// Round 9
// baseline (176.935 us; speedup 1.0000x reference)
//
#include <hip/hip_runtime.h>

// TinyRecursiveModel fused kernel, v9.
// = v8 math (pi-permuted weights -> no exchange, params via global/L2,
//   pkrtz pack) but SINGLE 16-row chain per wave -> 4096 waves = 16 waves/CU
//   (4/SIMD), vs v8's 2048 waves (2/SIMD). LDS 36864B x 4 blocks/CU fits.
//   Latency-bound -> TLP fix. __launch_bounds__(256,2) keeps VGPR budget 128.

using f16x8 = __attribute__((ext_vector_type(8))) _Float16;
using f32x4 = __attribute__((ext_vector_type(4))) float;

#define DI __device__ __forceinline__

namespace {

constexpr int RS = 144;   // LDS row stride bytes for weight mats (128B + 16B pad)
constexpr float EPS = 1e-5f;

DI unsigned pkrtz(float a, float b) {  // two f32 -> packed f16 pair (RTZ, 1 op)
#if __has_builtin(__builtin_amdgcn_cvt_pkrtz)
  return __builtin_bit_cast(unsigned, __builtin_amdgcn_cvt_pkrtz(a, b));
#else
  unsigned r;
  asm("v_cvt_pkrtz_f16_f32 %0, %1, %2" : "=v"(r) : "v"(a), "v"(b));
  return r;
#endif
}

DI f16x8 cvt8h(f32x4 a, f32x4 b) {  // RNE (weights/input staging)
  f16x8 r;
  r[0] = (_Float16)a[0]; r[1] = (_Float16)a[1];
  r[2] = (_Float16)a[2]; r[3] = (_Float16)a[3];
  r[4] = (_Float16)b[0]; r[5] = (_Float16)b[1];
  r[6] = (_Float16)b[2]; r[7] = (_Float16)b[3];
  return r;
}

DI unsigned pkmax0(unsigned t) {  // packed f16 relu
  unsigned r;
  asm("v_pk_max_f16 %0, %1, 0" : "=v"(r) : "v"(t));
  return r;
}

// ---- lane-group swaps for the LN cross-group reduction only ----
DI void swap16(unsigned& a, unsigned& b) {
#if __has_builtin(__builtin_amdgcn_permlane16_swap)
  auto r = __builtin_amdgcn_permlane16_swap(a, b, false, false);
  a = r[0]; b = r[1];
#else
  unsigned ax = (unsigned)__shfl_xor((int)a, 16);
  unsigned bx = (unsigned)__shfl_xor((int)b, 16);
  bool odd = (threadIdx.x & 16) != 0;
  unsigned na = odd ? bx : a;
  unsigned nb = odd ? b : ax;
  a = na; b = nb;
#endif
}
DI void swap32(unsigned& a, unsigned& b) {
#if __has_builtin(__builtin_amdgcn_permlane32_swap)
  auto r = __builtin_amdgcn_permlane32_swap(a, b, false, false);
  a = r[0]; b = r[1];
#else
  unsigned ax = (unsigned)__shfl_xor((int)a, 32);
  unsigned bx = (unsigned)__shfl_xor((int)b, 32);
  bool hi = (threadIdx.x & 32) != 0;
  unsigned na = hi ? bx : a;
  unsigned nb = hi ? b : ax;
  a = na; b = nb;
#endif
}

DI float reduce4(float x) {  // sum across the 4 g-groups (same l15)
  unsigned a = __builtin_bit_cast(unsigned, x), b = a;
  swap16(a, b);
  float x1 = __builtin_bit_cast(float, a) + __builtin_bit_cast(float, b);
  unsigned c = __builtin_bit_cast(unsigned, x1), d = c;
  swap32(c, d);
  return __builtin_bit_cast(float, c) + __builtin_bit_cast(float, d);
}

union BU {  // u[0..3] = b0 frag (k 0..31), u[4..7] = b1 frag (k 32..63)
  unsigned u[8];
  struct { f16x8 b0, b1; } f;
};

// D-layout acc -> B-operand; with pi-permuted weights the order is identity.
template <bool RELU>
DI void packacc(const f32x4 (&acc)[4], BU& o) {
#pragma unroll
  for (int tp = 0; tp < 4; ++tp) {
    unsigned p0 = pkrtz(acc[tp][0], acc[tp][1]);
    unsigned p1 = pkrtz(acc[tp][2], acc[tp][3]);
    if (RELU) { p0 = pkmax0(p0); p1 = pkmax0(p1); }
    o.u[2 * tp + 0] = p0;
    o.u[2 * tp + 1] = p1;
  }
}

struct WFrag { f16x8 f[4][2]; };  // [tp][khalf] A-frags (pi-permuted K-cols)

// pi: slot (s,g,j) <- feature 32s + 4g + j (j<4) / 32s+16+4g+(j-4) (j>=4).
DI WFrag loadW(const float* W, int l15, int g) {  // f32 row-major 64x64
  WFrag w;
#pragma unroll
  for (int tp = 0; tp < 4; ++tp)
#pragma unroll
    for (int s = 0; s < 2; ++s) {
      const float* p = W + (16 * tp + l15) * 64 + 32 * s + 4 * g;
      w.f[tp][s] = cvt8h(*(const f32x4*)p, *(const f32x4*)(p + 16));
    }
  return w;
}

DI f32x4 mfma(f16x8 a, f16x8 b, f32x4 c) {
  return __builtin_amdgcn_mfma_f32_16x16x32_f16(a, b, c, 0, 0, 0);
}

// Single-chain LayerNorm; gb: gamma at +0, beta at +64 (global/L2).
DI void lnorm(const f32x4 (&a)[4], const float* gb, int g, f32x4 (&h)[4]) {
  float s = 0.f, q = 0.f;
#pragma unroll
  for (int tp = 0; tp < 4; ++tp)
#pragma unroll
    for (int r = 0; r < 4; ++r) { float x = a[tp][r]; s += x; q = fmaf(x, x, q); }
  s = reduce4(s); q = reduce4(q);
  float mean = s * 0.015625f;
  float var  = fmaf(q, 0.015625f, -mean * mean);
  float rs   = rsqrtf(var + EPS);
  float u    = -mean * rs;
  const f32x4* gv = (const f32x4*)gb;
#pragma unroll
  for (int tp = 0; tp < 4; ++tp) {
    f32x4 gg = gv[4 * tp + g];
    f32x4 bb = gv[16 + 4 * tp + g];
#pragma unroll
    for (int r = 0; r < 4; ++r)
      h[tp][r] = fmaf(fmaf(a[tp][r], rs, u), gg[r], bb[r]);
  }
}

struct alignas(16) Smem {
  char mats[4][64 * RS];  // W1 l0, W1 l1, W2 l0, W2 l1 (f16, padded, pi-cols)
};

// One transformer layer, single chain. prm: [bvo|b1|b2|g1|be1|g2|be2] x 64.
DI void do_layer(f32x4 (&h)[4], BU& b, const WFrag& wvo, const char* w1b,
                 const char* w2b, const float* prm, int g) {
  asm("" : "+r"(prm));  // keep param loads in-loop (no giant LICM hoist)
  const f32x4* pv = (const f32x4*)prm;
  f32x4 a[4];
  // ---- P1: a = h + W_vo@h + b_vo ; h = LN1(a) ----
#pragma unroll
  for (int tp = 0; tp < 4; ++tp) {
    a[tp] = mfma(wvo.f[tp][1], b.f.b1, mfma(wvo.f[tp][0], b.f.b0, h[tp]));
    a[tp] += pv[4 * tp + g];
  }
  lnorm(a, prm + 192, g, h);
  packacc<false>(h, b);
  // ---- P2: t = relu(W1@h + b1) ----
#pragma unroll
  for (int tp = 0; tp < 4; ++tp) {
    f16x8 a0 = *(const f16x8*)(w1b + tp * 16 * RS);
    f16x8 a1 = *(const f16x8*)(w1b + tp * 16 * RS + 64);
    a[tp] = mfma(a1, b.f.b1, mfma(a0, b.f.b0, pv[16 + 4 * tp + g]));
  }
  packacc<true>(a, b);
  // ---- P3: a = h + W2@t + b2 ; h = LN2(a) ----
#pragma unroll
  for (int tp = 0; tp < 4; ++tp) {
    f16x8 a0 = *(const f16x8*)(w2b + tp * 16 * RS);
    f16x8 a1 = *(const f16x8*)(w2b + tp * 16 * RS + 64);
    a[tp] = mfma(a1, b.f.b1, mfma(a0, b.f.b0, h[tp]));
    a[tp] += pv[32 + 4 * tp + g];
  }
  lnorm(a, prm + 320, g, h);
  packacc<false>(h, b);
}

// ---------- precompute: W_vo, b_vo, and packed param table ----------
// ws layout (floats): [0..4095] W_vo l0, [4096..8191] W_vo l1,
// [8192..] params: per layer 448 = [bvo|b1|b2|g1|be1|g2|be2] x 64.
__global__ __launch_bounds__(256) void precompute_kernel(
    const float* __restrict__ Wqkv, const float* __restrict__ bqkv,
    const float* __restrict__ Wo, const float* __restrict__ bo,
    const float* __restrict__ b1, const float* __restrict__ b2,
    const float* __restrict__ ln1_g, const float* __restrict__ ln1_b,
    const float* __restrict__ ln2_g, const float* __restrict__ ln2_b,
    float* __restrict__ ws) {
  __shared__ float wv[4096];
  __shared__ float wo[4096];
  const int l = blockIdx.x;
  const float* Wv  = Wqkv + l * (192 * 64) + 128 * 64;
  const float* WoL = Wo + l * 4096;
  for (int e = threadIdx.x; e < 4096; e += 256) { wv[e] = Wv[e]; wo[e] = WoL[e]; }
  __syncthreads();
  float* wvo = ws + l * 4096;
  const int i = threadIdx.x >> 2, j0 = (threadIdx.x & 3) * 16;
  float acc[16];
#pragma unroll
  for (int jj = 0; jj < 16; ++jj) acc[jj] = 0.f;
  for (int k = 0; k < 64; ++k) {
    float a = wo[i * 64 + k];
#pragma unroll
    for (int jj = 0; jj < 16; ++jj) acc[jj] = fmaf(a, wv[k * 64 + j0 + jj], acc[jj]);
  }
#pragma unroll
  for (int jj = 0; jj < 16; ++jj) wvo[i * 64 + j0 + jj] = acc[jj];
  float* prm = ws + 2 * 4096 + l * 448;
  if (threadIdx.x < 64) {
    const int i2 = threadIdx.x;
    const float* bv = bqkv + l * 192 + 128;
    float s = bo[l * 64 + i2];
    for (int k = 0; k < 64; ++k) s = fmaf(wo[i2 * 64 + k], bv[k], s);
    prm[i2]       = s;                  // bvo
    prm[64 + i2]  = b1[l * 64 + i2];
    prm[128 + i2] = b2[l * 64 + i2];
    prm[192 + i2] = ln1_g[l * 64 + i2];
    prm[256 + i2] = ln1_b[l * 64 + i2];
    prm[320 + i2] = ln2_g[l * 64 + i2];
    prm[384 + i2] = ln2_b[l * 64 + i2];
  }
}

// ---------- main fused kernel ----------
// (256,2): compiler VGPR budget 128 (no v6-style spill). HW residency:
// single-chain ~110 VGPR and 36864B LDS -> 4 blocks/CU, 16 waves/CU.
__global__ __launch_bounds__(256, 2) void trm9_kernel(
    const float* __restrict__ x, const float* __restrict__ input_w,
    const float* __restrict__ input_b, const float* __restrict__ W1,
    const float* __restrict__ W2, const float* __restrict__ out_w,
    const float* __restrict__ out_b, const float* __restrict__ ws,
    float* __restrict__ out) {
  __shared__ Smem sm;
  const int tid = threadIdx.x;
  const int w = tid >> 6, lane = tid & 63;
  const int l15 = lane & 15, g = lane >> 4;
  const int row0 = blockIdx.x * 64 + w * 16;  // this wave's 16 rows

  // ---- stage W1/W2 (both layers) as f16, pi-permuted K-cols, padded ----
  {
    const float* srcs[4] = {W1, W1 + 4096, W2, W2 + 4096};
#pragma unroll
    for (int m = 0; m < 4; ++m) {
      char* dst = sm.mats[m];
      const float* src = srcs[m];
      for (int e = tid; e < 512; e += 256) {
        int row = e >> 3, q = e & 7, s = q >> 2, gq = q & 3;
        const float* p = src + row * 64 + 32 * s + 4 * gq;
        *(f16x8*)(dst + row * RS + 64 * s + 16 * gq) =
            cvt8h(*(const f32x4*)p, *(const f32x4*)(p + 16));
      }
    }
  }

  // ---- W_vo(l0,l1) fragments in registers (pi-permuted) ----
  WFrag wvo0 = loadW(ws, l15, g);
  WFrag wvo1 = loadW(ws + 4096, l15, g);

  const char* w1b0 = sm.mats[0] + l15 * RS + 16 * g;
  const char* w1b1 = sm.mats[1] + l15 * RS + 16 * g;
  const char* w2b0 = sm.mats[2] + l15 * RS + 16 * g;
  const char* w2b1 = sm.mats[3] + l15 * RS + 16 * g;
  const float* prm0 = ws + 2 * 4096;
  const float* prm1 = ws + 2 * 4096 + 448;

  // ---- input projection: h = x @ input_w^T + input_b (K=200) ----
  f32x4 h[4];
#pragma unroll
  for (int tp = 0; tp < 4; ++tp)
    h[tp] = *(const f32x4*)(input_b + 16 * tp + 4 * g);
  {
    const float* xr = x + (size_t)(row0 + l15) * 200;
    const f32x4 zero = {0.f, 0.f, 0.f, 0.f};
    for (int s7 = 0; s7 < 7; ++s7) {
      int kb = 32 * s7 + 8 * g;
      bool v0 = kb < 200;
      f32x4 xa0 = v0 ? *(const f32x4*)(xr + kb) : zero;
      f32x4 xa1 = v0 ? *(const f32x4*)(xr + kb + 4) : zero;
      f16x8 bf = cvt8h(xa0, xa1);
#pragma unroll
      for (int tp = 0; tp < 4; ++tp) {
        const float* wr = input_w + (16 * tp + l15) * 200;
        f32x4 wa = v0 ? *(const f32x4*)(wr + kb) : zero;
        f32x4 wb = v0 ? *(const f32x4*)(wr + kb + 4) : zero;
        h[tp] = mfma(cvt8h(wa, wb), bf, h[tp]);
      }
    }
  }
  BU b;
  packacc<false>(h, b);
  __syncthreads();  // weight mats staged; the only block barrier

  // ---- recurrence: 16 steps x 2 layers; no LDS writes, no fences ----
#pragma unroll 1
  for (int step = 0; step < 16; ++step) {
    do_layer(h, b, wvo0, w1b0, w2b0, prm0, g);
    do_layer(h, b, wvo1, w1b1, w2b1, prm1, g);
  }

  // ---- out = h . out_w + out_b ----
  float p = 0.f;
#pragma unroll
  for (int tp = 0; tp < 4; ++tp) {
    f32x4 ow = *(const f32x4*)(out_w + 16 * tp + 4 * g);
#pragma unroll
    for (int r = 0; r < 4; ++r) p = fmaf(h[tp][r], ow[r], p);
  }
  p += __shfl_xor(p, 16);
  p += __shfl_xor(p, 32);
  if (lane < 16) out[row0 + l15] = p + out_b[0];
}

}  // namespace

extern "C" void kernel_launch(void* const* d_in, const int* in_sizes, int n_in,
                              void* d_out, int out_size, void* d_ws, size_t ws_size,
                              hipStream_t stream) {
  const float* x       = (const float*)d_in[0];
  const float* input_w = (const float*)d_in[1];
  const float* input_b = (const float*)d_in[2];
  const float* Wqkv    = (const float*)d_in[3];
  const float* bqkv    = (const float*)d_in[4];
  const float* Wo      = (const float*)d_in[5];
  const float* bo      = (const float*)d_in[6];
  const float* ln1_g   = (const float*)d_in[7];
  const float* ln1_b   = (const float*)d_in[8];
  const float* W1      = (const float*)d_in[9];
  const float* b1      = (const float*)d_in[10];
  const float* W2      = (const float*)d_in[11];
  const float* b2      = (const float*)d_in[12];
  const float* ln2_g   = (const float*)d_in[13];
  const float* ln2_b   = (const float*)d_in[14];
  const float* out_w   = (const float*)d_in[15];
  const float* out_b   = (const float*)d_in[16];
  float* out = (float*)d_out;
  float* ws  = (float*)d_ws;

  hipLaunchKernelGGL(precompute_kernel, dim3(2), dim3(256), 0, stream,
                     Wqkv, bqkv, Wo, bo, b1, b2, ln1_g, ln1_b, ln2_g, ln2_b, ws);
  hipLaunchKernelGGL(trm9_kernel, dim3(1024), dim3(256), 0, stream,
                     x, input_w, input_b, W1, W2, out_w, out_b, ws, out);
}

// Round 10
// 166.522 us; speedup vs baseline: 1.0625x; 1.0625x over previous
//
#include <hip/hip_runtime.h>

// TinyRecursiveModel fused kernel, v10.
// vs v8 (108us): 4 independent 16-row chains per wave (64 rows/wave).
// Waves/CU is capped ~8 by the register footprint no matter the grid (v9
// lesson), so trade TLP for ILP: weight ds_reads + param loads amortized
// over 4 chains (per-CU LDS traffic halved vs v8), 4 parallel dependency
// streams hide MFMA/LN/rsqrt/L2 latencies within one wave.
// 128-thread blocks (2 waves), grid 512, __launch_bounds__(128,2) -> 256-reg
// budget, live set ~210, no spill (WRITE_SIZE is the sentinel).

using f16x8 = __attribute__((ext_vector_type(8))) _Float16;
using f32x4 = __attribute__((ext_vector_type(4))) float;

#define DI __device__ __forceinline__

namespace {

constexpr int RS = 144;   // LDS row stride bytes for weight mats (128B + 16B pad)
constexpr float EPS = 1e-5f;

DI unsigned pkrtz(float a, float b) {  // two f32 -> packed f16 pair (RTZ, 1 op)
#if __has_builtin(__builtin_amdgcn_cvt_pkrtz)
  return __builtin_bit_cast(unsigned, __builtin_amdgcn_cvt_pkrtz(a, b));
#else
  unsigned r;
  asm("v_cvt_pkrtz_f16_f32 %0, %1, %2" : "=v"(r) : "v"(a), "v"(b));
  return r;
#endif
}

DI f16x8 cvt8h(f32x4 a, f32x4 b) {  // RNE (weights/input staging)
  f16x8 r;
  r[0] = (_Float16)a[0]; r[1] = (_Float16)a[1];
  r[2] = (_Float16)a[2]; r[3] = (_Float16)a[3];
  r[4] = (_Float16)b[0]; r[5] = (_Float16)b[1];
  r[6] = (_Float16)b[2]; r[7] = (_Float16)b[3];
  return r;
}

DI unsigned pkmax0(unsigned t) {  // packed f16 relu
  unsigned r;
  asm("v_pk_max_f16 %0, %1, 0" : "=v"(r) : "v"(t));
  return r;
}

// ---- lane-group swaps for the LN cross-group reduction only ----
DI void swap16(unsigned& a, unsigned& b) {
#if __has_builtin(__builtin_amdgcn_permlane16_swap)
  auto r = __builtin_amdgcn_permlane16_swap(a, b, false, false);
  a = r[0]; b = r[1];
#else
  unsigned ax = (unsigned)__shfl_xor((int)a, 16);
  unsigned bx = (unsigned)__shfl_xor((int)b, 16);
  bool odd = (threadIdx.x & 16) != 0;
  unsigned na = odd ? bx : a;
  unsigned nb = odd ? b : ax;
  a = na; b = nb;
#endif
}
DI void swap32(unsigned& a, unsigned& b) {
#if __has_builtin(__builtin_amdgcn_permlane32_swap)
  auto r = __builtin_amdgcn_permlane32_swap(a, b, false, false);
  a = r[0]; b = r[1];
#else
  unsigned ax = (unsigned)__shfl_xor((int)a, 32);
  unsigned bx = (unsigned)__shfl_xor((int)b, 32);
  bool hi = (threadIdx.x & 32) != 0;
  unsigned na = hi ? bx : a;
  unsigned nb = hi ? b : ax;
  a = na; b = nb;
#endif
}

DI float reduce4(float x) {  // sum across the 4 g-groups (same l15)
  unsigned a = __builtin_bit_cast(unsigned, x), b = a;
  swap16(a, b);
  float x1 = __builtin_bit_cast(float, a) + __builtin_bit_cast(float, b);
  unsigned c = __builtin_bit_cast(unsigned, x1), d = c;
  swap32(c, d);
  return __builtin_bit_cast(float, c) + __builtin_bit_cast(float, d);
}

union BU {  // u[0..3] = b0 frag (k 0..31), u[4..7] = b1 frag (k 32..63)
  unsigned u[8];
  struct { f16x8 b0, b1; } f;
};

// D-layout acc -> B-operand; with pi-permuted weights the order is identity.
template <bool RELU>
DI void packacc(const f32x4 (&acc)[4], BU& o) {
#pragma unroll
  for (int tp = 0; tp < 4; ++tp) {
    unsigned p0 = pkrtz(acc[tp][0], acc[tp][1]);
    unsigned p1 = pkrtz(acc[tp][2], acc[tp][3]);
    if (RELU) { p0 = pkmax0(p0); p1 = pkmax0(p1); }
    o.u[2 * tp + 0] = p0;
    o.u[2 * tp + 1] = p1;
  }
}

struct WFrag { f16x8 f[4][2]; };  // [tp][khalf] A-frags (pi-permuted K-cols)

// pi: slot (s,g,j) <- feature 32s + 4g + j (j<4) / 32s+16+4g+(j-4) (j>=4).
DI WFrag loadW(const float* W, int l15, int g) {  // f32 row-major 64x64
  WFrag w;
#pragma unroll
  for (int tp = 0; tp < 4; ++tp)
#pragma unroll
    for (int s = 0; s < 2; ++s) {
      const float* p = W + (16 * tp + l15) * 64 + 32 * s + 4 * g;
      w.f[tp][s] = cvt8h(*(const f32x4*)p, *(const f32x4*)(p + 16));
    }
  return w;
}

DI f32x4 mfma(f16x8 a, f16x8 b, f32x4 c) {
  return __builtin_amdgcn_mfma_f32_16x16x32_f16(a, b, c, 0, 0, 0);
}

// 4-chain LayerNorm; gb: gamma at +0, beta at +64 (global/L2), loads shared.
DI void lnorm4(const f32x4 (&a0)[4], const f32x4 (&a1)[4],
               const f32x4 (&a2)[4], const f32x4 (&a3)[4],
               const float* gb, int g,
               f32x4 (&h0)[4], f32x4 (&h1)[4], f32x4 (&h2)[4], f32x4 (&h3)[4]) {
  float s0 = 0.f, q0 = 0.f, s1 = 0.f, q1 = 0.f;
  float s2 = 0.f, q2 = 0.f, s3 = 0.f, q3 = 0.f;
#pragma unroll
  for (int tp = 0; tp < 4; ++tp)
#pragma unroll
    for (int r = 0; r < 4; ++r) {
      float x0 = a0[tp][r]; s0 += x0; q0 = fmaf(x0, x0, q0);
      float x1 = a1[tp][r]; s1 += x1; q1 = fmaf(x1, x1, q1);
      float x2 = a2[tp][r]; s2 += x2; q2 = fmaf(x2, x2, q2);
      float x3 = a3[tp][r]; s3 += x3; q3 = fmaf(x3, x3, q3);
    }
  s0 = reduce4(s0); q0 = reduce4(q0);
  s1 = reduce4(s1); q1 = reduce4(q1);
  s2 = reduce4(s2); q2 = reduce4(q2);
  s3 = reduce4(s3); q3 = reduce4(q3);
  float m0 = s0 * 0.015625f, m1 = s1 * 0.015625f;
  float m2 = s2 * 0.015625f, m3 = s3 * 0.015625f;
  float r0 = rsqrtf(fmaf(q0, 0.015625f, -m0 * m0) + EPS);
  float r1 = rsqrtf(fmaf(q1, 0.015625f, -m1 * m1) + EPS);
  float r2 = rsqrtf(fmaf(q2, 0.015625f, -m2 * m2) + EPS);
  float r3 = rsqrtf(fmaf(q3, 0.015625f, -m3 * m3) + EPS);
  float u0 = -m0 * r0, u1 = -m1 * r1, u2 = -m2 * r2, u3 = -m3 * r3;
  const f32x4* gv = (const f32x4*)gb;
#pragma unroll
  for (int tp = 0; tp < 4; ++tp) {
    f32x4 gg = gv[4 * tp + g];
    f32x4 bb = gv[16 + 4 * tp + g];
#pragma unroll
    for (int r = 0; r < 4; ++r) {
      h0[tp][r] = fmaf(fmaf(a0[tp][r], r0, u0), gg[r], bb[r]);
      h1[tp][r] = fmaf(fmaf(a1[tp][r], r1, u1), gg[r], bb[r]);
      h2[tp][r] = fmaf(fmaf(a2[tp][r], r2, u2), gg[r], bb[r]);
      h3[tp][r] = fmaf(fmaf(a3[tp][r], r3, u3), gg[r], bb[r]);
    }
  }
}

struct alignas(16) Smem {
  char mats[4][64 * RS];  // W1 l0, W1 l1, W2 l0, W2 l1 (f16, padded, pi-cols)
};

// One transformer layer, 4 chains. prm: [bvo|b1|b2|g1|be1|g2|be2] x 64 f32.
DI void do_layer(f32x4 (&h0)[4], f32x4 (&h1)[4], f32x4 (&h2)[4], f32x4 (&h3)[4],
                 BU& b0, BU& b1, BU& b2, BU& b3, const WFrag& wvo,
                 const char* w1b, const char* w2b, const float* prm, int g) {
  asm("" : "+r"(prm));  // keep param loads per-layer (no giant LICM hoist)
  const f32x4* pv = (const f32x4*)prm;
  f32x4 a0[4], a1[4], a2[4], a3[4];
  // ---- P1: a = h + W_vo@h + b_vo ; h = LN1(a) ----
#pragma unroll
  for (int tp = 0; tp < 4; ++tp) {
    f32x4 bv = pv[4 * tp + g];
    a0[tp] = mfma(wvo.f[tp][1], b0.f.b1, mfma(wvo.f[tp][0], b0.f.b0, h0[tp])) + bv;
    a1[tp] = mfma(wvo.f[tp][1], b1.f.b1, mfma(wvo.f[tp][0], b1.f.b0, h1[tp])) + bv;
    a2[tp] = mfma(wvo.f[tp][1], b2.f.b1, mfma(wvo.f[tp][0], b2.f.b0, h2[tp])) + bv;
    a3[tp] = mfma(wvo.f[tp][1], b3.f.b1, mfma(wvo.f[tp][0], b3.f.b0, h3[tp])) + bv;
  }
  lnorm4(a0, a1, a2, a3, prm + 192, g, h0, h1, h2, h3);
  packacc<false>(h0, b0); packacc<false>(h1, b1);
  packacc<false>(h2, b2); packacc<false>(h3, b3);
  // ---- P2: t = relu(W1@h + b1) ----
#pragma unroll
  for (int tp = 0; tp < 4; ++tp) {
    f16x8 wa0 = *(const f16x8*)(w1b + tp * 16 * RS);
    f16x8 wa1 = *(const f16x8*)(w1b + tp * 16 * RS + 64);
    f32x4 cin = pv[16 + 4 * tp + g];
    a0[tp] = mfma(wa1, b0.f.b1, mfma(wa0, b0.f.b0, cin));
    a1[tp] = mfma(wa1, b1.f.b1, mfma(wa0, b1.f.b0, cin));
    a2[tp] = mfma(wa1, b2.f.b1, mfma(wa0, b2.f.b0, cin));
    a3[tp] = mfma(wa1, b3.f.b1, mfma(wa0, b3.f.b0, cin));
  }
  packacc<true>(a0, b0); packacc<true>(a1, b1);
  packacc<true>(a2, b2); packacc<true>(a3, b3);
  // ---- P3: a = h + W2@t + b2 ; h = LN2(a) ----
#pragma unroll
  for (int tp = 0; tp < 4; ++tp) {
    f16x8 wa0 = *(const f16x8*)(w2b + tp * 16 * RS);
    f16x8 wa1 = *(const f16x8*)(w2b + tp * 16 * RS + 64);
    f32x4 bv = pv[32 + 4 * tp + g];
    a0[tp] = mfma(wa1, b0.f.b1, mfma(wa0, b0.f.b0, h0[tp])) + bv;
    a1[tp] = mfma(wa1, b1.f.b1, mfma(wa0, b1.f.b0, h1[tp])) + bv;
    a2[tp] = mfma(wa1, b2.f.b1, mfma(wa0, b2.f.b0, h2[tp])) + bv;
    a3[tp] = mfma(wa1, b3.f.b1, mfma(wa0, b3.f.b0, h3[tp])) + bv;
  }
  lnorm4(a0, a1, a2, a3, prm + 320, g, h0, h1, h2, h3);
  packacc<false>(h0, b0); packacc<false>(h1, b1);
  packacc<false>(h2, b2); packacc<false>(h3, b3);
}

// ---------- precompute: W_vo, b_vo, and packed param table ----------
// ws layout (floats): [0..4095] W_vo l0, [4096..8191] W_vo l1,
// [8192..] params: per layer 448 = [bvo|b1|b2|g1|be1|g2|be2] x 64.
__global__ __launch_bounds__(256) void precompute_kernel(
    const float* __restrict__ Wqkv, const float* __restrict__ bqkv,
    const float* __restrict__ Wo, const float* __restrict__ bo,
    const float* __restrict__ b1, const float* __restrict__ b2,
    const float* __restrict__ ln1_g, const float* __restrict__ ln1_b,
    const float* __restrict__ ln2_g, const float* __restrict__ ln2_b,
    float* __restrict__ ws) {
  __shared__ float wv[4096];
  __shared__ float wo[4096];
  const int l = blockIdx.x;
  const float* Wv  = Wqkv + l * (192 * 64) + 128 * 64;
  const float* WoL = Wo + l * 4096;
  for (int e = threadIdx.x; e < 4096; e += 256) { wv[e] = Wv[e]; wo[e] = WoL[e]; }
  __syncthreads();
  float* wvo = ws + l * 4096;
  const int i = threadIdx.x >> 2, j0 = (threadIdx.x & 3) * 16;
  float acc[16];
#pragma unroll
  for (int jj = 0; jj < 16; ++jj) acc[jj] = 0.f;
  for (int k = 0; k < 64; ++k) {
    float a = wo[i * 64 + k];
#pragma unroll
    for (int jj = 0; jj < 16; ++jj) acc[jj] = fmaf(a, wv[k * 64 + j0 + jj], acc[jj]);
  }
#pragma unroll
  for (int jj = 0; jj < 16; ++jj) wvo[i * 64 + j0 + jj] = acc[jj];
  float* prm = ws + 2 * 4096 + l * 448;
  if (threadIdx.x < 64) {
    const int i2 = threadIdx.x;
    const float* bv = bqkv + l * 192 + 128;
    float s = bo[l * 64 + i2];
    for (int k = 0; k < 64; ++k) s = fmaf(wo[i2 * 64 + k], bv[k], s);
    prm[i2]       = s;                  // bvo
    prm[64 + i2]  = b1[l * 64 + i2];
    prm[128 + i2] = b2[l * 64 + i2];
    prm[192 + i2] = ln1_g[l * 64 + i2];
    prm[256 + i2] = ln1_b[l * 64 + i2];
    prm[320 + i2] = ln2_g[l * 64 + i2];
    prm[384 + i2] = ln2_b[l * 64 + i2];
  }
}

// ---------- main fused kernel ----------
// 128 threads (2 waves), 64 rows/wave (4 chains), grid 512 -> 2 blocks/CU,
// 4 waves/CU. (128,2): compiler budget 256 regs; live set ~210.
__global__ __launch_bounds__(128, 2) void trm10_kernel(
    const float* __restrict__ x, const float* __restrict__ input_w,
    const float* __restrict__ input_b, const float* __restrict__ W1,
    const float* __restrict__ W2, const float* __restrict__ out_w,
    const float* __restrict__ out_b, const float* __restrict__ ws,
    float* __restrict__ out) {
  __shared__ Smem sm;
  const int tid = threadIdx.x;
  const int w = tid >> 6, lane = tid & 63;
  const int l15 = lane & 15, g = lane >> 4;
  const int row0 = blockIdx.x * 128 + w * 64;  // chains at +0,+16,+32,+48

  // ---- stage W1/W2 (both layers) as f16, pi-permuted K-cols, padded ----
  {
    const float* srcs[4] = {W1, W1 + 4096, W2, W2 + 4096};
#pragma unroll
    for (int m = 0; m < 4; ++m) {
      char* dst = sm.mats[m];
      const float* src = srcs[m];
      for (int e = tid; e < 512; e += 128) {
        int row = e >> 3, q = e & 7, s = q >> 2, gq = q & 3;
        const float* p = src + row * 64 + 32 * s + 4 * gq;
        *(f16x8*)(dst + row * RS + 64 * s + 16 * gq) =
            cvt8h(*(const f32x4*)p, *(const f32x4*)(p + 16));
      }
    }
  }

  // ---- W_vo(l0,l1) fragments in registers (pi-permuted) ----
  WFrag wvo0 = loadW(ws, l15, g);
  WFrag wvo1 = loadW(ws + 4096, l15, g);

  const char* w1b0 = sm.mats[0] + l15 * RS + 16 * g;
  const char* w1b1 = sm.mats[1] + l15 * RS + 16 * g;
  const char* w2b0 = sm.mats[2] + l15 * RS + 16 * g;
  const char* w2b1 = sm.mats[3] + l15 * RS + 16 * g;
  const float* prm0 = ws + 2 * 4096;
  const float* prm1 = ws + 2 * 4096 + 448;

  // ---- input projection: h = x @ input_w^T + input_b (K=200) ----
  f32x4 h0[4], h1[4], h2[4], h3[4];
#pragma unroll
  for (int tp = 0; tp < 4; ++tp) {
    f32x4 ib = *(const f32x4*)(input_b + 16 * tp + 4 * g);
    h0[tp] = ib; h1[tp] = ib; h2[tp] = ib; h3[tp] = ib;
  }
  {
    const float* xr0 = x + (size_t)(row0 + l15) * 200;
    const float* xr1 = xr0 + 16 * 200;
    const float* xr2 = xr0 + 32 * 200;
    const float* xr3 = xr0 + 48 * 200;
    const f32x4 zero = {0.f, 0.f, 0.f, 0.f};
    for (int s7 = 0; s7 < 7; ++s7) {
      int kb = 32 * s7 + 8 * g;
      bool v0 = kb < 200;
      f16x8 bf0 = cvt8h(v0 ? *(const f32x4*)(xr0 + kb) : zero,
                        v0 ? *(const f32x4*)(xr0 + kb + 4) : zero);
      f16x8 bf1 = cvt8h(v0 ? *(const f32x4*)(xr1 + kb) : zero,
                        v0 ? *(const f32x4*)(xr1 + kb + 4) : zero);
      f16x8 bf2 = cvt8h(v0 ? *(const f32x4*)(xr2 + kb) : zero,
                        v0 ? *(const f32x4*)(xr2 + kb + 4) : zero);
      f16x8 bf3 = cvt8h(v0 ? *(const f32x4*)(xr3 + kb) : zero,
                        v0 ? *(const f32x4*)(xr3 + kb + 4) : zero);
#pragma unroll
      for (int tp = 0; tp < 4; ++tp) {
        const float* wr = input_w + (16 * tp + l15) * 200;
        f32x4 wa = v0 ? *(const f32x4*)(wr + kb) : zero;
        f32x4 wb = v0 ? *(const f32x4*)(wr + kb + 4) : zero;
        f16x8 af = cvt8h(wa, wb);
        h0[tp] = mfma(af, bf0, h0[tp]);
        h1[tp] = mfma(af, bf1, h1[tp]);
        h2[tp] = mfma(af, bf2, h2[tp]);
        h3[tp] = mfma(af, bf3, h3[tp]);
      }
    }
  }
  BU b0, b1, b2, b3;
  packacc<false>(h0, b0); packacc<false>(h1, b1);
  packacc<false>(h2, b2); packacc<false>(h3, b3);
  __syncthreads();  // weight mats staged; the only block barrier

  // ---- recurrence: 16 steps x 2 layers; no LDS writes, no fences ----
#pragma unroll 1
  for (int step = 0; step < 16; ++step) {
    do_layer(h0, h1, h2, h3, b0, b1, b2, b3, wvo0, w1b0, w2b0, prm0, g);
    do_layer(h0, h1, h2, h3, b0, b1, b2, b3, wvo1, w1b1, w2b1, prm1, g);
  }

  // ---- out = h . out_w + out_b ----
  float p0 = 0.f, p1 = 0.f, p2 = 0.f, p3 = 0.f;
#pragma unroll
  for (int tp = 0; tp < 4; ++tp) {
    f32x4 ow = *(const f32x4*)(out_w + 16 * tp + 4 * g);
#pragma unroll
    for (int r = 0; r < 4; ++r) {
      p0 = fmaf(h0[tp][r], ow[r], p0);
      p1 = fmaf(h1[tp][r], ow[r], p1);
      p2 = fmaf(h2[tp][r], ow[r], p2);
      p3 = fmaf(h3[tp][r], ow[r], p3);
    }
  }
  p0 += __shfl_xor(p0, 16); p0 += __shfl_xor(p0, 32);
  p1 += __shfl_xor(p1, 16); p1 += __shfl_xor(p1, 32);
  p2 += __shfl_xor(p2, 16); p2 += __shfl_xor(p2, 32);
  p3 += __shfl_xor(p3, 16); p3 += __shfl_xor(p3, 32);
  if (lane < 16) {
    float ob = out_b[0];
    out[row0 + l15]      = p0 + ob;
    out[row0 + 16 + l15] = p1 + ob;
    out[row0 + 32 + l15] = p2 + ob;
    out[row0 + 48 + l15] = p3 + ob;
  }
}

}  // namespace

extern "C" void kernel_launch(void* const* d_in, const int* in_sizes, int n_in,
                              void* d_out, int out_size, void* d_ws, size_t ws_size,
                              hipStream_t stream) {
  const float* x       = (const float*)d_in[0];
  const float* input_w = (const float*)d_in[1];
  const float* input_b = (const float*)d_in[2];
  const float* Wqkv    = (const float*)d_in[3];
  const float* bqkv    = (const float*)d_in[4];
  const float* Wo      = (const float*)d_in[5];
  const float* bo      = (const float*)d_in[6];
  const float* ln1_g   = (const float*)d_in[7];
  const float* ln1_b   = (const float*)d_in[8];
  const float* W1      = (const float*)d_in[9];
  const float* b1      = (const float*)d_in[10];
  const float* W2      = (const float*)d_in[11];
  const float* b2      = (const float*)d_in[12];
  const float* ln2_g   = (const float*)d_in[13];
  const float* ln2_b   = (const float*)d_in[14];
  const float* out_w   = (const float*)d_in[15];
  const float* out_b   = (const float*)d_in[16];
  float* out = (float*)d_out;
  float* ws  = (float*)d_ws;

  hipLaunchKernelGGL(precompute_kernel, dim3(2), dim3(256), 0, stream,
                     Wqkv, bqkv, Wo, bo, b1, b2, ln1_g, ln1_b, ln2_g, ln2_b, ws);
  hipLaunchKernelGGL(trm10_kernel, dim3(512), dim3(128), 0, stream,
                     x, input_w, input_b, W1, W2, out_w, out_b, ws, out);
}

// Round 12
// 107.361 us; speedup vs baseline: 1.6480x; 1.5510x over previous
//
#include <hip/hip_runtime.h>

// TinyRecursiveModel fused kernel, v12.
// = v8 (108us verified champion: dual 16-row chains/wave, pi-permuted
//   weights -> no exchange, params via global/L2, pkrtz pack) with ONE
//   change: rsqrtf -> __builtin_amdgcn_rsqf (single v_rsq_f32) on the LN
//   critical path. v11's packed-f32 VOP3P asm is abandoned (numerics fail).

using f16x8 = __attribute__((ext_vector_type(8))) _Float16;
using f32x4 = __attribute__((ext_vector_type(4))) float;

#define DI __device__ __forceinline__

namespace {

constexpr int RS = 144;   // LDS row stride bytes for weight mats (128B + 16B pad)
constexpr float EPS = 1e-5f;

DI float rsq(float x) {  // single v_rsq_f32; ~2^-22 rel err, fine vs f16 quant
#if __has_builtin(__builtin_amdgcn_rsqf)
  return __builtin_amdgcn_rsqf(x);
#else
  float r;
  asm("v_rsq_f32 %0, %1" : "=v"(r) : "v"(x));
  return r;
#endif
}

DI unsigned pkrtz(float a, float b) {  // two f32 -> packed f16 pair (RTZ, 1 op)
#if __has_builtin(__builtin_amdgcn_cvt_pkrtz)
  return __builtin_bit_cast(unsigned, __builtin_amdgcn_cvt_pkrtz(a, b));
#else
  unsigned r;
  asm("v_cvt_pkrtz_f16_f32 %0, %1, %2" : "=v"(r) : "v"(a), "v"(b));
  return r;
#endif
}

DI f16x8 cvt8h(f32x4 a, f32x4 b) {  // RNE (weights/input staging)
  f16x8 r;
  r[0] = (_Float16)a[0]; r[1] = (_Float16)a[1];
  r[2] = (_Float16)a[2]; r[3] = (_Float16)a[3];
  r[4] = (_Float16)b[0]; r[5] = (_Float16)b[1];
  r[6] = (_Float16)b[2]; r[7] = (_Float16)b[3];
  return r;
}

DI unsigned pkmax0(unsigned t) {  // packed f16 relu
  unsigned r;
  asm("v_pk_max_f16 %0, %1, 0" : "=v"(r) : "v"(t));
  return r;
}

// ---- lane-group swaps for the LN cross-group reduction only ----
DI void swap16(unsigned& a, unsigned& b) {
#if __has_builtin(__builtin_amdgcn_permlane16_swap)
  auto r = __builtin_amdgcn_permlane16_swap(a, b, false, false);
  a = r[0]; b = r[1];
#else
  unsigned ax = (unsigned)__shfl_xor((int)a, 16);
  unsigned bx = (unsigned)__shfl_xor((int)b, 16);
  bool odd = (threadIdx.x & 16) != 0;
  unsigned na = odd ? bx : a;
  unsigned nb = odd ? b : ax;
  a = na; b = nb;
#endif
}
DI void swap32(unsigned& a, unsigned& b) {
#if __has_builtin(__builtin_amdgcn_permlane32_swap)
  auto r = __builtin_amdgcn_permlane32_swap(a, b, false, false);
  a = r[0]; b = r[1];
#else
  unsigned ax = (unsigned)__shfl_xor((int)a, 32);
  unsigned bx = (unsigned)__shfl_xor((int)b, 32);
  bool hi = (threadIdx.x & 32) != 0;
  unsigned na = hi ? bx : a;
  unsigned nb = hi ? b : ax;
  a = na; b = nb;
#endif
}

DI float reduce4(float x) {  // sum across the 4 g-groups (same l15)
  unsigned a = __builtin_bit_cast(unsigned, x), b = a;
  swap16(a, b);
  float x1 = __builtin_bit_cast(float, a) + __builtin_bit_cast(float, b);
  unsigned c = __builtin_bit_cast(unsigned, x1), d = c;
  swap32(c, d);
  return __builtin_bit_cast(float, c) + __builtin_bit_cast(float, d);
}

union BU {  // u[0..3] = b0 frag (k 0..31), u[4..7] = b1 frag (k 32..63)
  unsigned u[8];
  struct { f16x8 b0, b1; } f;
};

// D-layout acc -> B-operand; with pi-permuted weights the order is identity.
template <bool RELU>
DI void packacc(const f32x4 (&acc)[4], BU& o) {
#pragma unroll
  for (int tp = 0; tp < 4; ++tp) {
    unsigned p0 = pkrtz(acc[tp][0], acc[tp][1]);
    unsigned p1 = pkrtz(acc[tp][2], acc[tp][3]);
    if (RELU) { p0 = pkmax0(p0); p1 = pkmax0(p1); }
    o.u[2 * tp + 0] = p0;
    o.u[2 * tp + 1] = p1;
  }
}

struct WFrag { f16x8 f[4][2]; };  // [tp][khalf] A-frags (pi-permuted K-cols)

// pi: slot (s,g,j) <- feature 32s + 4g + j (j<4) / 32s+16+4g+(j-4) (j>=4).
DI WFrag loadW(const float* W, int l15, int g) {  // f32 row-major 64x64
  WFrag w;
#pragma unroll
  for (int tp = 0; tp < 4; ++tp)
#pragma unroll
    for (int s = 0; s < 2; ++s) {
      const float* p = W + (16 * tp + l15) * 64 + 32 * s + 4 * g;
      w.f[tp][s] = cvt8h(*(const f32x4*)p, *(const f32x4*)(p + 16));
    }
  return w;
}

DI f32x4 mfma(f16x8 a, f16x8 b, f32x4 c) {
  return __builtin_amdgcn_mfma_f32_16x16x32_f16(a, b, c, 0, 0, 0);
}

// Dual-chain LayerNorm: stats per chain, shared gamma/beta loads (global/L2).
DI void lnorm2(const f32x4 (&aA)[4], const f32x4 (&aB)[4], const float* gb,
               int g, f32x4 (&hA)[4], f32x4 (&hB)[4]) {
  float sA = 0.f, qA = 0.f, sB = 0.f, qB = 0.f;
#pragma unroll
  for (int tp = 0; tp < 4; ++tp)
#pragma unroll
    for (int r = 0; r < 4; ++r) {
      float xa = aA[tp][r]; sA += xa; qA = fmaf(xa, xa, qA);
      float xb = aB[tp][r]; sB += xb; qB = fmaf(xb, xb, qB);
    }
  sA = reduce4(sA); qA = reduce4(qA);
  sB = reduce4(sB); qB = reduce4(qB);
  float mA = sA * 0.015625f, mB = sB * 0.015625f;
  float rA = rsq(fmaf(qA, 0.015625f, -mA * mA) + EPS);
  float rB = rsq(fmaf(qB, 0.015625f, -mB * mB) + EPS);
  float uA = -mA * rA, uB = -mB * rB;
  const f32x4* gv = (const f32x4*)gb;
#pragma unroll
  for (int tp = 0; tp < 4; ++tp) {
    f32x4 gg = gv[4 * tp + g];
    f32x4 bb = gv[16 + 4 * tp + g];
#pragma unroll
    for (int r = 0; r < 4; ++r) {
      hA[tp][r] = fmaf(fmaf(aA[tp][r], rA, uA), gg[r], bb[r]);
      hB[tp][r] = fmaf(fmaf(aB[tp][r], rB, uB), gg[r], bb[r]);
    }
  }
}

struct alignas(16) Smem {
  char mats[4][64 * RS];  // W1 l0, W1 l1, W2 l0, W2 l1 (f16, padded, pi-cols)
};

// One transformer layer, both chains. prm: [bvo|b1|b2|g1|be1|g2|be2] x 64.
DI void do_layer(f32x4 (&hA)[4], f32x4 (&hB)[4], BU& bA, BU& bB,
                 const WFrag& wvo, const char* w1b, const char* w2b,
                 const float* prm, int g) {
  asm("" : "+r"(prm));  // keep param loads in-loop (no giant LICM hoist)
  const f32x4* pv = (const f32x4*)prm;
  f32x4 aA[4], aB[4];
  // ---- P1: a = h + W_vo@h + b_vo ; h = LN1(a) ----
#pragma unroll
  for (int tp = 0; tp < 4; ++tp) {
    aA[tp] = mfma(wvo.f[tp][1], bA.f.b1, mfma(wvo.f[tp][0], bA.f.b0, hA[tp]));
    aB[tp] = mfma(wvo.f[tp][1], bB.f.b1, mfma(wvo.f[tp][0], bB.f.b0, hB[tp]));
    f32x4 bv = pv[4 * tp + g];
    aA[tp] += bv; aB[tp] += bv;
  }
  lnorm2(aA, aB, prm + 192, g, hA, hB);
  packacc<false>(hA, bA); packacc<false>(hB, bB);
  // ---- P2: t = relu(W1@h + b1) ----
#pragma unroll
  for (int tp = 0; tp < 4; ++tp) {
    f16x8 a0 = *(const f16x8*)(w1b + tp * 16 * RS);
    f16x8 a1 = *(const f16x8*)(w1b + tp * 16 * RS + 64);
    f32x4 cin = pv[16 + 4 * tp + g];
    aA[tp] = mfma(a1, bA.f.b1, mfma(a0, bA.f.b0, cin));
    aB[tp] = mfma(a1, bB.f.b1, mfma(a0, bB.f.b0, cin));
  }
  packacc<true>(aA, bA); packacc<true>(aB, bB);
  // ---- P3: a = h + W2@t + b2 ; h = LN2(a) ----
#pragma unroll
  for (int tp = 0; tp < 4; ++tp) {
    f16x8 a0 = *(const f16x8*)(w2b + tp * 16 * RS);
    f16x8 a1 = *(const f16x8*)(w2b + tp * 16 * RS + 64);
    aA[tp] = mfma(a1, bA.f.b1, mfma(a0, bA.f.b0, hA[tp]));
    aB[tp] = mfma(a1, bB.f.b1, mfma(a0, bB.f.b0, hB[tp]));
    f32x4 bv = pv[32 + 4 * tp + g];
    aA[tp] += bv; aB[tp] += bv;
  }
  lnorm2(aA, aB, prm + 320, g, hA, hB);
  packacc<false>(hA, bA); packacc<false>(hB, bB);
}

// ---------- precompute: W_vo, b_vo, and packed param table ----------
// ws layout (floats): [0..4095] W_vo l0, [4096..8191] W_vo l1,
// [8192..] params: per layer 448 = [bvo|b1|b2|g1|be1|g2|be2] x 64.
__global__ __launch_bounds__(256) void precompute_kernel(
    const float* __restrict__ Wqkv, const float* __restrict__ bqkv,
    const float* __restrict__ Wo, const float* __restrict__ bo,
    const float* __restrict__ b1, const float* __restrict__ b2,
    const float* __restrict__ ln1_g, const float* __restrict__ ln1_b,
    const float* __restrict__ ln2_g, const float* __restrict__ ln2_b,
    float* __restrict__ ws) {
  __shared__ float wv[4096];
  __shared__ float wo[4096];
  const int l = blockIdx.x;
  const float* Wv  = Wqkv + l * (192 * 64) + 128 * 64;
  const float* WoL = Wo + l * 4096;
  for (int e = threadIdx.x; e < 4096; e += 256) { wv[e] = Wv[e]; wo[e] = WoL[e]; }
  __syncthreads();
  float* wvo = ws + l * 4096;
  const int i = threadIdx.x >> 2, j0 = (threadIdx.x & 3) * 16;
  float acc[16];
#pragma unroll
  for (int jj = 0; jj < 16; ++jj) acc[jj] = 0.f;
  for (int k = 0; k < 64; ++k) {
    float a = wo[i * 64 + k];
#pragma unroll
    for (int jj = 0; jj < 16; ++jj) acc[jj] = fmaf(a, wv[k * 64 + j0 + jj], acc[jj]);
  }
#pragma unroll
  for (int jj = 0; jj < 16; ++jj) wvo[i * 64 + j0 + jj] = acc[jj];
  float* prm = ws + 2 * 4096 + l * 448;
  if (threadIdx.x < 64) {
    const int i2 = threadIdx.x;
    const float* bv = bqkv + l * 192 + 128;
    float s = bo[l * 64 + i2];
    for (int k = 0; k < 64; ++k) s = fmaf(wo[i2 * 64 + k], bv[k], s);
    prm[i2]       = s;                  // bvo
    prm[64 + i2]  = b1[l * 64 + i2];
    prm[128 + i2] = b2[l * 64 + i2];
    prm[192 + i2] = ln1_g[l * 64 + i2];
    prm[256 + i2] = ln1_b[l * 64 + i2];
    prm[320 + i2] = ln2_g[l * 64 + i2];
    prm[384 + i2] = ln2_b[l * 64 + i2];
  }
}

// ---------- main fused kernel ----------
__global__ __launch_bounds__(256, 2) void trm12_kernel(
    const float* __restrict__ x, const float* __restrict__ input_w,
    const float* __restrict__ input_b, const float* __restrict__ W1,
    const float* __restrict__ W2, const float* __restrict__ out_w,
    const float* __restrict__ out_b, const float* __restrict__ ws,
    float* __restrict__ out) {
  __shared__ Smem sm;
  const int tid = threadIdx.x;
  const int w = tid >> 6, lane = tid & 63;
  const int l15 = lane & 15, g = lane >> 4;
  const int row0 = blockIdx.x * 128 + w * 32;  // chain A rows row0.., B +16

  // ---- stage W1/W2 (both layers) as f16, pi-permuted K-cols, padded ----
  {
    const float* srcs[4] = {W1, W1 + 4096, W2, W2 + 4096};
#pragma unroll
    for (int m = 0; m < 4; ++m) {
      char* dst = sm.mats[m];
      const float* src = srcs[m];
      for (int e = tid; e < 512; e += 256) {
        int row = e >> 3, q = e & 7, s = q >> 2, gq = q & 3;
        const float* p = src + row * 64 + 32 * s + 4 * gq;
        *(f16x8*)(dst + row * RS + 64 * s + 16 * gq) =
            cvt8h(*(const f32x4*)p, *(const f32x4*)(p + 16));
      }
    }
  }

  // ---- W_vo(l0,l1) fragments in registers (pi-permuted) ----
  WFrag wvo0 = loadW(ws, l15, g);
  WFrag wvo1 = loadW(ws + 4096, l15, g);

  const char* w1b0 = sm.mats[0] + l15 * RS + 16 * g;
  const char* w1b1 = sm.mats[1] + l15 * RS + 16 * g;
  const char* w2b0 = sm.mats[2] + l15 * RS + 16 * g;
  const char* w2b1 = sm.mats[3] + l15 * RS + 16 * g;
  const float* prm0 = ws + 2 * 4096;
  const float* prm1 = ws + 2 * 4096 + 448;

  // ---- input projection: h = x @ input_w^T + input_b (K=200) ----
  f32x4 hA[4], hB[4];
#pragma unroll
  for (int tp = 0; tp < 4; ++tp) {
    f32x4 ib = *(const f32x4*)(input_b + 16 * tp + 4 * g);
    hA[tp] = ib; hB[tp] = ib;
  }
  {
    const float* xA = x + (size_t)(row0 + l15) * 200;
    const float* xB = xA + 16 * 200;
    const f32x4 zero = {0.f, 0.f, 0.f, 0.f};
    for (int s7 = 0; s7 < 7; ++s7) {
      int kb = 32 * s7 + 8 * g;
      bool v0 = kb < 200;
      f32x4 xa0 = v0 ? *(const f32x4*)(xA + kb) : zero;
      f32x4 xa1 = v0 ? *(const f32x4*)(xA + kb + 4) : zero;
      f32x4 xb0 = v0 ? *(const f32x4*)(xB + kb) : zero;
      f32x4 xb1 = v0 ? *(const f32x4*)(xB + kb + 4) : zero;
      f16x8 bfA = cvt8h(xa0, xa1);
      f16x8 bfB = cvt8h(xb0, xb1);
#pragma unroll
      for (int tp = 0; tp < 4; ++tp) {
        const float* wr = input_w + (16 * tp + l15) * 200;
        f32x4 wa = v0 ? *(const f32x4*)(wr + kb) : zero;
        f32x4 wb = v0 ? *(const f32x4*)(wr + kb + 4) : zero;
        f16x8 af = cvt8h(wa, wb);
        hA[tp] = mfma(af, bfA, hA[tp]);
        hB[tp] = mfma(af, bfB, hB[tp]);
      }
    }
  }
  BU bA, bB;
  packacc<false>(hA, bA); packacc<false>(hB, bB);
  __syncthreads();  // weight mats staged; the only block barrier

  // ---- recurrence: 16 steps x 2 layers; no LDS writes, no fences ----
#pragma unroll 1
  for (int step = 0; step < 16; ++step) {
    do_layer(hA, hB, bA, bB, wvo0, w1b0, w2b0, prm0, g);
    do_layer(hA, hB, bA, bB, wvo1, w1b1, w2b1, prm1, g);
  }

  // ---- out = h . out_w + out_b ----
  float pA = 0.f, pB = 0.f;
#pragma unroll
  for (int tp = 0; tp < 4; ++tp) {
    f32x4 ow = *(const f32x4*)(out_w + 16 * tp + 4 * g);
#pragma unroll
    for (int r = 0; r < 4; ++r) {
      pA = fmaf(hA[tp][r], ow[r], pA);
      pB = fmaf(hB[tp][r], ow[r], pB);
    }
  }
  pA += __shfl_xor(pA, 16); pA += __shfl_xor(pA, 32);
  pB += __shfl_xor(pB, 16); pB += __shfl_xor(pB, 32);
  if (lane < 16) {
    float ob = out_b[0];
    out[row0 + l15]      = pA + ob;
    out[row0 + 16 + l15] = pB + ob;
  }
}

}  // namespace

extern "C" void kernel_launch(void* const* d_in, const int* in_sizes, int n_in,
                              void* d_out, int out_size, void* d_ws, size_t ws_size,
                              hipStream_t stream) {
  const float* x       = (const float*)d_in[0];
  const float* input_w = (const float*)d_in[1];
  const float* input_b = (const float*)d_in[2];
  const float* Wqkv    = (const float*)d_in[3];
  const float* bqkv    = (const float*)d_in[4];
  const float* Wo      = (const float*)d_in[5];
  const float* bo      = (const float*)d_in[6];
  const float* ln1_g   = (const float*)d_in[7];
  const float* ln1_b   = (const float*)d_in[8];
  const float* W1      = (const float*)d_in[9];
  const float* b1      = (const float*)d_in[10];
  const float* W2      = (const float*)d_in[11];
  const float* b2      = (const float*)d_in[12];
  const float* ln2_g   = (const float*)d_in[13];
  const float* ln2_b   = (const float*)d_in[14];
  const float* out_w   = (const float*)d_in[15];
  const float* out_b   = (const float*)d_in[16];
  float* out = (float*)d_out;
  float* ws  = (float*)d_ws;

  hipLaunchKernelGGL(precompute_kernel, dim3(2), dim3(256), 0, stream,
                     Wqkv, bqkv, Wo, bo, b1, b2, ln1_g, ln1_b, ln2_g, ln2_b, ws);
  hipLaunchKernelGGL(trm12_kernel, dim3(512), dim3(256), 0, stream,
                     x, input_w, input_b, W1, W2, out_w, out_b, ws, out);
}